// Round 16
// baseline (4212.200 us; speedup 1.0000x reference)
//
#include <hip/hip_runtime.h>
#include <hip/hip_bf16.h>

typedef unsigned short u16;
typedef _Float16 f16x8 __attribute__((ext_vector_type(8)));
typedef float f32x4 __attribute__((ext_vector_type(4)));

#define DEV __device__ __forceinline__

DEV u16 f2h(float f) { _Float16 h = (_Float16)f; u16 u; __builtin_memcpy(&u, &h, 2); return u; }
DEV float h2f(u16 u) { _Float16 h; __builtin_memcpy(&h, &u, 2); return (float)h; }
DEV void splitf(float v, u16& hi, u16& lo) { hi = f2h(v); lo = f2h(v - h2f(hi)); }
DEV float sigm(float x) { return 1.f / (1.f + __expf(-x)); }
// direct HBM->LDS 16B DMA: per-lane global src, wave-uniform LDS base + lane*16
DEV void gload16(const u16* g, u16* l) {
  __builtin_amdgcn_global_load_lds((const __attribute__((address_space(1))) void*)g,
                                   (__attribute__((address_space(3))) void*)l, 16, 0, 0);
}

static const int TT = 2048;

// ---------------- workspace layout (bytes) ----------------
static const size_t OFF_AUGF   = 0;                                   // float2 512*512 (2MB) pass-1 in-place
static const size_t OFF_AUG    = OFF_AUGF   + (size_t)512*512*8;      // double2 512*512 (4MB) pass-2 in-place
static const size_t OFF_BINV2  = OFF_AUG    + (size_t)512*512*16;     // double2 2 x 64*64 (parity)
static const size_t OFF_MCOPY2 = OFF_BINV2  + (size_t)2*64*64*16;     // double2 2 x 512*64 (parity)
static const size_t OFF_PIV    = OFF_MCOPY2 + (size_t)2*512*64*16;    // double2 64*512
static const size_t OFF_TAB    = OFF_PIV    + (size_t)64*512*16;      // double4 512
static const size_t OFF_WCATH  = OFF_TAB    + (size_t)512*32;         // f16 512*1024
static const size_t OFF_WCATL  = OFF_WCATH  + (size_t)512*1024*2;
static const size_t OFF_MIXH   = OFF_WCATL  + (size_t)512*1024*2;     // f16 1024*1024
static const size_t OFF_MIXL   = OFF_MIXH   + (size_t)1024*1024*2;
static const size_t OFF_PROJH  = OFF_MIXL   + (size_t)1024*1024*2;    // f16 1024*1024 (transposed)
static const size_t OFF_PROJL  = OFF_PROJH  + (size_t)1024*1024*2;
static const size_t OFF_B1TH   = OFF_PROJL  + (size_t)1024*1024*2;    // f16 512*1024
static const size_t OFF_B1TL   = OFF_B1TH   + (size_t)512*1024*2;
static const size_t OFF_B2TH   = OFF_B1TL   + (size_t)512*1024*2;
static const size_t OFF_B2TL   = OFF_B2TH   + (size_t)512*1024*2;
static const size_t OFF_BTMIXH = OFF_B2TL   + (size_t)512*1024*2;     // f16 1024*512
static const size_t OFF_BTMIXL = OFF_BTMIXH + (size_t)1024*512*2;
static const size_t OFF_BTFH   = OFF_BTMIXL + (size_t)1024*512*2;     // f16 512*1536
static const size_t OFF_BTFL   = OFF_BTFH   + (size_t)512*1536*2;
static const size_t OFF_BIAS2  = OFF_BTFL   + (size_t)512*1536*2;     // f32 512
static const size_t OFF_CARRY  = OFF_BIAS2  + (size_t)512*4;          // float2 4096*16
static const size_t OFF_PREF   = OFF_CARRY  + (size_t)4096*16*8;      // float2 4096*16
static const size_t OFF_XINF   = OFF_PREF   + (size_t)4096*16*8;      // f32 16384*1024 (64MB)
static const size_t OFF_ACATH  = OFF_XINF   + (size_t)16384*1024*4;   // f16 16384*1536 (48MB)
static const size_t OFF_ACATL  = OFF_ACATH  + (size_t)16384*1536*2;   // f16 16384*1536 (48MB)

// ---------------- converts ----------------
__global__ __launch_bounds__(256) void k_split_f32(const float* __restrict__ s, u16* __restrict__ dh,
                                                   u16* __restrict__ dl, int n4) {
  int g = blockIdx.x * 256 + threadIdx.x;
  if (g >= n4) return;
  float4 v = ((const float4*)s)[g];
  ushort4 h, l;
  splitf(v.x, h.x, l.x); splitf(v.y, h.y, l.y); splitf(v.z, h.z, l.z); splitf(v.w, h.w, l.w);
  ((ushort4*)dh)[g] = h;
  ((ushort4*)dl)[g] = l;
}

// x (16384x512 f32) -> ACAT hi/lo cols [0,512) with row stride 1536
__global__ __launch_bounds__(256) void k_x_to_acat(const float* __restrict__ x, u16* __restrict__ ah,
                                                   u16* __restrict__ al) {
  int g = blockIdx.x * 256 + threadIdx.x;   // 2097152 float4s
  if (g >= 2097152) return;
  float4 v = ((const float4*)x)[g];
  int idx = g * 4;
  int row = idx >> 9, col = idx & 511;
  ushort4 h, l;
  splitf(v.x, h.x, l.x); splitf(v.y, h.y, l.y); splitf(v.z, h.z, l.z); splitf(v.w, h.w, l.w);
  *(ushort4*)(ah + (size_t)row*1536 + col) = h;
  *(ushort4*)(al + (size_t)row*1536 + col) = l;
}

// proj_w (1024x1024 f32) -> hi/lo transposed: out[j][c] = in[c][j]
__global__ __launch_bounds__(256) void k_transpose_1024(const float* __restrict__ in, u16* __restrict__ oh,
                                                        u16* __restrict__ ol) {
  __shared__ float s[64][65];
  int lx = threadIdx.x & 63, ly = threadIdx.x >> 6;
#pragma unroll
  for (int i = 0; i < 16; ++i) {
    int c = blockIdx.y*64 + ly*16 + i;
    s[ly*16 + i][lx] = in[(size_t)c*1024 + blockIdx.x*64 + lx];
  }
  __syncthreads();
#pragma unroll
  for (int i = 0; i < 16; ++i) {
    int j = blockIdx.x*64 + ly*16 + i;
    u16 h, l; splitf(s[lx][ly*16 + i], h, l);
    oh[(size_t)j*1024 + blockIdx.y*64 + lx] = h;
    ol[(size_t)j*1024 + blockIdx.y*64 + lx] = l;
  }
}

// ---------------- build (I+K), K = A - A^H  (f32, 512 cols — pass 1 is a plain inversion) ----------------
__global__ __launch_bounds__(256) void k_build_aug_f(const float* __restrict__ vre, const float* __restrict__ vim,
                                                     float2* __restrict__ aug) {
  int g = blockIdx.x * 256 + threadIdx.x;   // 512*512
  if (g >= 512*512) return;
  int i = g >> 9, j = g & 511;
  float sre = vre[i*512 + j] - vre[j*512 + i];
  float sim = vim[i*512 + j] + vim[j*512 + i];
  float idd = (i == j) ? 1.f : 0.f;
  aug[g] = make_float2(idd + sre, sim);
}

// ---------------- 64x64 in-register GJ inversion core (R11/R13-verified v3 math) ----------------
// thread (r = tid>>4, q = tid&15) holds a[0..3] = A[r][4q..4q+3]. 1 barrier/pivot, no shfl.
template<typename T2, typename TR>
DEV void inv64_reg(T2* a, T2* mcol /*2*64*/, T2* praw /*2*68*/, T2* __restrict__ BINVout) {
  const int tid = threadIdx.x;
  const int r = tid >> 4, q = tid & 15;
  if (q == 0) mcol[0*64 + r] = a[0];
  if (r == 0) {
#pragma unroll
    for (int jj = 0; jj < 4; ++jj) { int j = q*4 + jj; praw[0*68 + j + (j >> 4)] = a[jj]; }
  }
  __syncthreads();
  for (int p = 0; p < 64; ++p) {
    const int bu = p & 1;
    T2 pd = praw[bu*68 + p + (p >> 4)];
    TR inv = TR(1) / (pd.x*pd.x + pd.y*pd.y);
    T2 pinv; pinv.x = pd.x*inv; pinv.y = -pd.y*inv;
    T2 mraw = mcol[bu*64 + r];
    T2 g; g.x = mraw.x*pinv.x - mraw.y*pinv.y; g.y = mraw.x*pinv.y + mraw.y*pinv.x;
    if (r == p) {
#pragma unroll
      for (int jj = 0; jj < 4; ++jj) {
        int j = q*4 + jj;
        T2 v;
        if (j == p) v = pinv;
        else { T2 pr = praw[bu*68 + j + (j >> 4)]; v.x = pr.x*pinv.x - pr.y*pinv.y; v.y = pr.x*pinv.y + pr.y*pinv.x; }
        a[jj] = v;
      }
    } else {
#pragma unroll
      for (int jj = 0; jj < 4; ++jj) {
        int j = q*4 + jj;
        if (j == p) { a[jj].x = -g.x; a[jj].y = -g.y; }
        else {
          T2 pr = praw[bu*68 + j + (j >> 4)];
          a[jj].x -= g.x*pr.x - g.y*pr.y;
          a[jj].y -= g.x*pr.y + g.y*pr.x;
        }
      }
    }
    if (p < 63) {
      const int nbu = bu ^ 1;
      if (q == ((p + 1) >> 2)) {
        const int loc = (p + 1) & 3;
#pragma unroll
        for (int jj = 0; jj < 4; ++jj) if (jj == loc) mcol[nbu*64 + r] = a[jj];   // static index (rule #20)
      }
      if (r == p + 1) {
#pragma unroll
        for (int jj = 0; jj < 4; ++jj) { int j = q*4 + jj; praw[nbu*68 + j + (j >> 4)] = a[jj]; }
      }
    }
    __syncthreads();
  }
#pragma unroll
  for (int jj = 0; jj < 4; ++jj) BINVout[(size_t)r*64 + q*4 + jj] = a[jj];
}

// ---------------- pass prologue: BINV(par 0) + MCOPY(par 0) for step 0 ----------------
template<typename T2, typename TR>
__global__ __launch_bounds__(1024) void gj_inv64_p(const T2* __restrict__ AUG, T2* __restrict__ BINV,
                                                   T2* __restrict__ MCOPY) {
  if (blockIdx.x > 0) {
    int b = blockIdx.x - 1;
    for (int l = threadIdx.x; l < 4096; l += 1024) {
      int rr = l >> 6, cc = l & 63;
      MCOPY[(size_t)(b*64 + rr)*64 + cc] = AUG[(size_t)(b*64 + rr)*512 + cc];
    }
    return;
  }
  __shared__ T2 mcol[2*64];
  __shared__ T2 praw[2*68];
  const int tid = threadIdx.x;
  const int r = tid >> 4, q = tid & 15;
  T2 a[4];
#pragma unroll
  for (int jj = 0; jj < 4; ++jj) a[jj] = AUG[(size_t)r*512 + q*4 + jj];
  inv64_reg<T2, TR>(a, mcol, praw, BINV);
}

// P[0:64][cols] = Binv @ AUG[k0:k0+64][cols] for the 7 non-pivot 64-col chunks.
template<typename T2>
__global__ __launch_bounds__(256) void gj_trans_t(const T2* __restrict__ AUG, const T2* __restrict__ BINV,
                                                  T2* __restrict__ PIV, int k0, int s) {
  __shared__ T2 binv[64][16];
  int tid = threadIdx.x;
  int cj = blockIdx.x + (blockIdx.x >= s ? 1 : 0);   // skip pivot chunk
  int col = cj*64 + (tid & 63);
  int rsub = tid >> 6;
  T2 acc[16];
#pragma unroll
  for (int i = 0; i < 16; ++i) { acc[i].x = 0; acc[i].y = 0; }
  for (int kc = 0; kc < 4; ++kc) {
    for (int l = tid; l < 1024; l += 256) {
      int rr = l >> 4, cc = l & 15;
      binv[rr][cc] = BINV[(size_t)rr*64 + kc*16 + cc];
    }
    __syncthreads();
#pragma unroll 4
    for (int kk = 0; kk < 16; ++kk) {
      T2 av = AUG[(size_t)(k0 + kc*16 + kk)*512 + col];
#pragma unroll
      for (int i = 0; i < 16; ++i) {
        T2 bv = binv[rsub*16 + i][kk];
        acc[i].x += bv.x*av.x - bv.y*av.y;
        acc[i].y += bv.x*av.y + bv.y*av.x;
      }
    }
    __syncthreads();
  }
#pragma unroll
  for (int i = 0; i < 16; ++i) PIV[(size_t)(rsub*16 + i)*512 + col] = acc[i];
}

// ---------------- fused in-place rank-64 update + snapshots + lookahead inversion ----------------
// Grid (8 cols, 8 rowgroups) x 1024 thr, 64x64 tile each. R12 update math; multipliers from
// parity MCOPY snapshot; pivot chunk overwritten with -M*Binv / Binv. Blocks cj==s+1 write the
// next-parity MCOPY; block (s+1,s+1) runs inv64_reg on its fresh tile into next-parity BINV.
template<typename T2, typename TR>
__global__ __launch_bounds__(1024) void gj_upinv(T2* __restrict__ AUG, const T2* __restrict__ PIV,
                                                 T2* __restrict__ BINV2, T2* __restrict__ MCOPY2, int s) {
  __shared__ T2 multc[64][16];
  __shared__ T2 pivc[16][64];
  __shared__ T2 mcol[2*64];
  __shared__ T2 praw[2*68];
  const int cj = blockIdx.x, rg = blockIdx.y;
  const int par = s & 1;
  const T2* __restrict__ BINV = BINV2 + (size_t)par*4096;
  const T2* __restrict__ MC   = MCOPY2 + (size_t)par*512*64;
  T2* __restrict__ BINVn = BINV2 + (size_t)(par ^ 1)*4096;
  T2* __restrict__ MCn   = MCOPY2 + (size_t)(par ^ 1)*512*64;
  const int tid = threadIdx.x;
  const int r = tid >> 4, q4 = (tid & 15) * 4;
  const int grow = rg*64 + r;
  const bool ispiv = (cj == s);
  T2 a[4];
  if (rg == s) {
    // pivot row band: new values are the scaled pivot rows (Binv for the pivot chunk)
#pragma unroll
    for (int jj = 0; jj < 4; ++jj)
      a[jj] = ispiv ? BINV[(size_t)r*64 + q4 + jj] : PIV[(size_t)r*512 + cj*64 + q4 + jj];
  } else {
    if (ispiv) {
#pragma unroll
      for (int jj = 0; jj < 4; ++jj) { a[jj].x = 0; a[jj].y = 0; }
    } else {
#pragma unroll
      for (int jj = 0; jj < 4; ++jj) a[jj] = AUG[(size_t)grow*512 + cj*64 + q4 + jj];
    }
    for (int kc = 0; kc < 4; ++kc) {
      { int rr = tid >> 4, kk = tid & 15;
        multc[rr][kk] = MC[(size_t)(rg*64 + rr)*64 + kc*16 + kk]; }
      { int rr = tid >> 6, cc = tid & 63;
        pivc[rr][cc] = ispiv ? BINV[(size_t)(kc*16 + rr)*64 + cc]
                             : PIV[(size_t)(kc*16 + rr)*512 + cj*64 + cc]; }
      __syncthreads();
#pragma unroll 4
      for (int k2 = 0; k2 < 16; ++k2) {
        T2 m = multc[r][k2];
#pragma unroll
        for (int jj = 0; jj < 4; ++jj) {
          T2 pv = pivc[k2][q4 + jj];
          a[jj].x -= m.x*pv.x - m.y*pv.y;
          a[jj].y -= m.x*pv.y + m.y*pv.x;
        }
      }
      __syncthreads();
    }
  }
#pragma unroll
  for (int jj = 0; jj < 4; ++jj) AUG[(size_t)grow*512 + cj*64 + q4 + jj] = a[jj];
  if (s < 7) {
    if (cj == s + 1) {
#pragma unroll
      for (int jj = 0; jj < 4; ++jj) MCn[(size_t)grow*64 + q4 + jj] = a[jj];
      if (rg == s + 1) {
        __syncthreads();   // LDS staging done; reuse mcol/praw for the inversion
        inv64_reg<T2, TR>(a, mcol, praw, BINVn);
      }
    }
  }
}

// ---------------- W build: V = 2Z - I (Z = (I+K)^-1), + reference f32 DFT phase ----------------
__global__ __launch_bounds__(256) void k_build_w(const float2* __restrict__ augf, const float* __restrict__ lsig,
                                                 const float* __restrict__ dw, double2* __restrict__ w64,
                                                 u16* __restrict__ wch, u16* __restrict__ wcl) {
  int g = blockIdx.x * 256 + threadIdx.x;
  if (g >= 512*512) return;
  int k = g >> 9, j = g & 511;
  float2 Z = augf[(size_t)k*512 + j];
  double Vre = 2.0*(double)Z.x - ((k == j) ? 1.0 : 0.0);
  double Vim = 2.0*(double)Z.y;
  double S = exp((double)lsig[j]);
  double al = 1.0 / (1.0 + exp(-(double)dw[0]));
  double sc = S * (1.0 - al);
  const float n2pi = (float)(-2.0 * 3.14159265358979323846);
  float nk = (float)(k * j);
  float ph32 = (n2pi * nk) / 512.0f;
  double sn, cs; sincos((double)ph32, &sn, &cs);
  float snf = (float)sn, csf = (float)cs;
  float rsq = sqrtf(512.0f);
  float dre = csf / rsq;
  float dimv = snf / rsq;
  double2 w = make_double2(Vre*sc + (double)dre*al, Vim*sc + (double)dimv*al);
  w64[(size_t)k*512 + j] = w;
  u16 h, l;
  splitf((float)w.x, h, l);
  wch[(size_t)k*1024 + j] = h;  wcl[(size_t)k*1024 + j] = l;
  splitf((float)w.y, h, l);
  wch[(size_t)k*1024 + 512 + j] = h;  wcl[(size_t)k*1024 + 512 + j] = l;
}

// ---------------- per-d constants (t_decay, forcing) in f64 ----------------
__global__ __launch_bounds__(256) void k_const512(const float* __restrict__ lamre, const float* __restrict__ lamim,
                                                  double4* __restrict__ tab) {
  int g = blockIdx.x * 256 + threadIdx.x;
  if (g >= 512) return;
  double lr = fmin(fmax((double)lamre[g], -0.3), 0.3);
  double li = (double)lamim[g];
  double e = exp(lr);
  double sn, cs; sincos(li, &sn, &cs);
  double tdre = e*cs, tdim = e*sn;
  double sgn = (lr + 1e-12) >= 0.0 ? 1.0 : -1.0;
  double lsr = lr + 1e-8*sgn, lsi = li;
  double numr = tdre - 1.0, numi = tdim;
  double idn = 1.0 / (lsr*lsr + lsi*lsi);
  double fr = (numr*lsr + numi*lsi)*idn;
  double fi = (numi*lsr - numr*lsi)*idn;
  tab[g] = make_double4(tdre, tdim, fr, fi);
}

// B1T[e][m]=Re(t_m Winv[m,e]), B1T[e][512+m]=-Im(...); B2T same with f_m  (hi/lo)
__global__ __launch_bounds__(256) void k_build_tb(const double2* __restrict__ winv, const double4* __restrict__ tab,
                                                  u16* __restrict__ b1h, u16* __restrict__ b1l,
                                                  u16* __restrict__ b2h, u16* __restrict__ b2l) {
  int g = blockIdx.x * 256 + threadIdx.x;   // 512*512, e fast
  if (g >= 512*512) return;
  int e = g & 511, m = g >> 9;
  double2 wv = winv[(size_t)m*512 + e];
  double4 tb = tab[m];
  double twre = tb.x*wv.x - tb.y*wv.y, twim = tb.x*wv.y + tb.y*wv.x;
  double fwre = tb.z*wv.x - tb.w*wv.y, fwim = tb.z*wv.y + tb.w*wv.x;
  u16 h, l;
  splitf((float)twre, h, l);  b1h[(size_t)e*1024 + m] = h;        b1l[(size_t)e*1024 + m] = l;
  splitf((float)-twim, h, l); b1h[(size_t)e*1024 + 512 + m] = h;  b1l[(size_t)e*1024 + 512 + m] = l;
  splitf((float)fwre, h, l);  b2h[(size_t)e*1024 + m] = h;        b2l[(size_t)e*1024 + m] = l;
  splitf((float)-fwim, h, l); b2h[(size_t)e*1024 + 512 + m] = h;  b2l[(size_t)e*1024 + 512 + m] = l;
}

// bias2[e] = Re( sum_d (projb[d]+i projb[512+d]) * f_d * Winv[d,e] )  — one block per e
__global__ __launch_bounds__(256) void k_bias2(const double2* __restrict__ winv, const double4* __restrict__ tab,
                                               const float* __restrict__ projb, float* __restrict__ bias2) {
  int e = blockIdx.x;
  int t = threadIdx.x;
  double acc = 0.0;
  for (int d = t; d < 512; d += 256) {
    double2 wv = winv[(size_t)d*512 + e];
    double4 tb = tab[d];
    double fwre = tb.z*wv.x - tb.w*wv.y;
    double fwim = tb.z*wv.y + tb.w*wv.x;
    acc += (double)projb[d]*fwre - (double)projb[512 + d]*fwim;
  }
#pragma unroll
  for (int off = 32; off; off >>= 1) acc += __shfl_down(acc, off, 64);
  __shared__ double red[4];
  if ((t & 63) == 0) red[t >> 6] = acc;
  __syncthreads();
  if (t == 0) bias2[e] = (float)(red[0] + red[1] + red[2] + red[3]);
}

// ---------------- split-f16 MFMA GEMM: C = (Ah+Al)(Bh+Bl)^T, drop Al*Bl ----------------
// Staging via global_load_lds (no VGPR staging, no spill); XCD-chunk block swizzle.
// EPI: 0 = hi/lo f16 store; 2/3 = f32 store + bias
template<int K, int NOUT, int EPI, int LDA, int LDO>
__global__ __launch_bounds__(256) void gemm3(const u16* __restrict__ Ah, const u16* __restrict__ Al,
                                             const u16* __restrict__ Bh, const u16* __restrict__ Bl,
                                             u16* __restrict__ outH, u16* __restrict__ outL,
                                             float* __restrict__ outF, const float* __restrict__ bias) {
  __shared__ alignas(16) u16 Ash[128*64];
  __shared__ alignas(16) u16 Asl[128*64];
  __shared__ alignas(16) u16 Bsh[128*64];
  __shared__ alignas(16) u16 Bsl[128*64];
  const int tid = threadIdx.x;
  const int lane = tid & 63, wid = tid >> 6;
  const int wr = wid >> 1, wc = wid & 1;
  const int nwg = gridDim.x * gridDim.y;
  const int flatb = blockIdx.y * gridDim.x + blockIdx.x;
  const int chunk = nwg >> 3;
  const int swz = (flatb & 7) * chunk + (flatb >> 3);
  const int rowTile = (swz / gridDim.x) * 128;
  const int colTile = (swz % gridDim.x) * 128;
  f32x4 zz = {0.f, 0.f, 0.f, 0.f};
  f32x4 acc[4][4];
#pragma unroll
  for (int m = 0; m < 4; ++m)
#pragma unroll
    for (int n = 0; n < 4; ++n) acc[m][n] = zz;

  const int KT = K / 64;
  for (int kt = 0; kt < KT; ++kt) {
    const int k0 = kt * 64;
    __syncthreads();   // previous tile fully consumed
#pragma unroll
    for (int i = 0; i < 4; ++i) {
      int flat = i*256 + tid;
      int ar = flat >> 3;
      int as = (flat & 7) ^ (ar & 7);       // pre-swizzled global slot
      size_t aoff = (size_t)(rowTile + ar)*LDA + (k0 + as*8);
      size_t boff = (size_t)(colTile + ar)*K   + (k0 + as*8);
      int lb = (i*256 + (tid & ~63)) * 8;   // wave-uniform LDS base (u16 units)
      gload16(Ah + aoff, Ash + lb);
      gload16(Al + aoff, Asl + lb);
      gload16(Bh + boff, Bsh + lb);
      gload16(Bl + boff, Bsl + lb);
    }
    __syncthreads();   // drains vmcnt before LDS reads
#pragma unroll
    for (int ks = 0; ks < 2; ++ks) {
      f16x8 afh[4], afl[4], bfh[4], bfl[4];
#pragma unroll
      for (int m = 0; m < 4; ++m) {
        int row = wr*64 + m*16 + (lane & 15);
        int off = row*128 + (((ks*4 + (lane >> 4)) ^ (row & 7)) << 4);
        afh[m] = *(const f16x8*)((const char*)Ash + off);
        afl[m] = *(const f16x8*)((const char*)Asl + off);
      }
#pragma unroll
      for (int n = 0; n < 4; ++n) {
        int row = wc*64 + n*16 + (lane & 15);
        int off = row*128 + (((ks*4 + (lane >> 4)) ^ (row & 7)) << 4);
        bfh[n] = *(const f16x8*)((const char*)Bsh + off);
        bfl[n] = *(const f16x8*)((const char*)Bsl + off);
      }
#pragma unroll
      for (int m = 0; m < 4; ++m)
#pragma unroll
        for (int n = 0; n < 4; ++n) {
          acc[m][n] = __builtin_amdgcn_mfma_f32_16x16x32_f16(afl[m], bfh[n], acc[m][n], 0, 0, 0);
          acc[m][n] = __builtin_amdgcn_mfma_f32_16x16x32_f16(afh[m], bfl[n], acc[m][n], 0, 0, 0);
          acc[m][n] = __builtin_amdgcn_mfma_f32_16x16x32_f16(afh[m], bfh[n], acc[m][n], 0, 0, 0);
        }
    }
  }
  const int colBase = colTile + wc*64;
  const int rowBase = rowTile + wr*64 + (lane >> 4)*4;
#pragma unroll
  for (int n = 0; n < 4; ++n) {
    int col = colBase + n*16 + (lane & 15);
    float bv = (EPI >= 2) ? bias[col] : 0.f;
#pragma unroll
    for (int m = 0; m < 4; ++m) {
#pragma unroll
      for (int j = 0; j < 4; ++j) {
        int row = rowBase + m*16 + j;
        float v = acc[m][n][j] + bv;
        if (EPI >= 2) {
          outF[(size_t)row*LDO + col] = v;
        } else {
          u16 h, l; splitf(v, h, l);
          outH[(size_t)row*LDO + col] = h;
          outL[(size_t)row*LDO + col] = l;
        }
      }
    }
  }
}

// ---------------- chunked linear scan along T (XIN is f32) ----------------
__global__ __launch_bounds__(256) void k_scan1(const float* __restrict__ xin, const float* __restrict__ dre_,
                                               const float* __restrict__ dim_, float2* __restrict__ carry) {
  int g = blockIdx.x * 256 + threadIdx.x;   // 65536
  int d = g & 511; int rr = g >> 9; int b = rr & 7; int c = rr >> 3;
  float dre = sigm(dre_[d]);
  float dim = dim_[d];
  size_t base = ((size_t)(b*TT + c*128))*1024 + d;
  float sre = 0.f, sim = 0.f;
  for (int t = 0; t < 128; ++t) {
    float xre = xin[base];
    float xim = xin[base + 512];
    float nre = dre*sre - dim*sim + xre;
    float nim = dre*sim + dim*sre + xim;
    sre = nre; sim = nim;
    base += 1024;
  }
  carry[((size_t)(b*512 + d))*16 + c] = make_float2(sre, sim);
}

__global__ __launch_bounds__(256) void k_scan2(const float* __restrict__ dre_, const float* __restrict__ dim_,
                                               const float2* __restrict__ carry, float2* __restrict__ pref) {
  int g = blockIdx.x * 256 + threadIdx.x;   // 4096
  int d = g & 511; int b = g >> 9;
  float dre = sigm(dre_[d]);
  float dim = dim_[d];
  float are = dre, aim = dim;
#pragma unroll
  for (int i = 0; i < 7; ++i) { float nr = are*are - aim*aim; float ni = 2.f*are*aim; are = nr; aim = ni; }
  float sre = 0.f, sim = 0.f;
  size_t base = ((size_t)(b*512 + d))*16;
  for (int c = 0; c < 16; ++c) {
    pref[base + c] = make_float2(sre, sim);
    float2 cr = carry[base + c];
    float nr = are*sre - aim*sim + cr.x;
    float ni = are*sim + aim*sre + cr.y;
    sre = nr; sim = ni;
  }
}

// writes states into ACAT hi/lo cols [512,1536)
__global__ __launch_bounds__(256) void k_scan3(const float* __restrict__ xin, const float* __restrict__ dre_,
                                               const float* __restrict__ dim_, const float2* __restrict__ pref,
                                               u16* __restrict__ ah, u16* __restrict__ al) {
  int g = blockIdx.x * 256 + threadIdx.x;   // 65536
  int d = g & 511; int rr = g >> 9; int b = rr & 7; int c = rr >> 3;
  float dre = sigm(dre_[d]);
  float dim = dim_[d];
  float2 p0 = pref[((size_t)(b*512 + d))*16 + c];
  float sre = p0.x, sim = p0.y;
  size_t base  = ((size_t)(b*TT + c*128))*1024 + d;
  size_t base2 = ((size_t)(b*TT + c*128))*1536 + d;
  for (int t = 0; t < 128; ++t) {
    float xre = xin[base];
    float xim = xin[base + 512];
    float nre = dre*sre - dim*sim + xre;
    float nim = dre*sim + dim*sre + xim;
    sre = nre; sim = nim;
    u16 h, l;
    splitf(sre, h, l); ah[base2 + 512]  = h; al[base2 + 512]  = l;
    splitf(sim, h, l); ah[base2 + 1024] = h; al[base2 + 1024] = l;
    base += 1024; base2 += 1536;
  }
}

// ---------------- launch ----------------
extern "C" void kernel_launch(void* const* d_in, const int* in_sizes, int n_in,
                              void* d_out, int out_size, void* d_ws, size_t ws_size,
                              hipStream_t stream) {
  (void)in_sizes; (void)n_in; (void)out_size; (void)ws_size;
  const float* x     = (const float*)d_in[0];
  const float* vre   = (const float*)d_in[1];
  const float* vim   = (const float*)d_in[2];
  const float* lsig  = (const float*)d_in[3];
  const float* dw    = (const float*)d_in[4];
  const float* decre = (const float*)d_in[5];
  const float* decim = (const float*)d_in[6];
  const float* mixw  = (const float*)d_in[7];
  const float* mixb  = (const float*)d_in[8];
  const float* projw = (const float*)d_in[9];
  const float* projb = (const float*)d_in[10];
  const float* lamre = (const float*)d_in[11];
  const float* lamim = (const float*)d_in[12];
  float* out = (float*)d_out;
  char* ws = (char*)d_ws;

  float2*  AUGF    = (float2*)(ws + OFF_AUGF);
  double2* AUG     = (double2*)(ws + OFF_AUG);
  double2* BINV2   = (double2*)(ws + OFF_BINV2);
  float2*  BINV2F  = (float2*)(ws + OFF_BINV2);
  double2* MCOPY2  = (double2*)(ws + OFF_MCOPY2);
  float2*  MCOPY2F = (float2*)(ws + OFF_MCOPY2);
  double2* PIV     = (double2*)(ws + OFF_PIV);
  float2*  PIVF    = (float2*)(ws + OFF_PIV);
  double4* TAB     = (double4*)(ws + OFF_TAB);
  u16*    WCATH  = (u16*)(ws + OFF_WCATH);
  u16*    WCATL  = (u16*)(ws + OFF_WCATL);
  u16*    MIXH   = (u16*)(ws + OFF_MIXH);
  u16*    MIXL   = (u16*)(ws + OFF_MIXL);
  u16*    PROJH  = (u16*)(ws + OFF_PROJH);
  u16*    PROJL  = (u16*)(ws + OFF_PROJL);
  u16*    B1TH   = (u16*)(ws + OFF_B1TH);
  u16*    B1TL   = (u16*)(ws + OFF_B1TL);
  u16*    B2TH   = (u16*)(ws + OFF_B2TH);
  u16*    B2TL   = (u16*)(ws + OFF_B2TL);
  u16*    BTMIXH = (u16*)(ws + OFF_BTMIXH);
  u16*    BTMIXL = (u16*)(ws + OFF_BTMIXL);
  u16*    BTFH   = (u16*)(ws + OFF_BTFH);
  u16*    BTFL   = (u16*)(ws + OFF_BTFL);
  float*  BIAS2  = (float*)(ws + OFF_BIAS2);
  float2* CARRY  = (float2*)(ws + OFF_CARRY);
  float2* PREF   = (float2*)(ws + OFF_PREF);
  float*  XINF   = (float*)(ws + OFF_XINF);
  u16*    ACATH  = (u16*)(ws + OFF_ACATH);
  u16*    ACATL  = (u16*)(ws + OFF_ACATL);

  // independent converts / tables
  k_const512<<<2, 256, 0, stream>>>(lamre, lamim, TAB);
  k_x_to_acat<<<8192, 256, 0, stream>>>(x, ACATH, ACATL);
  k_split_f32<<<1024, 256, 0, stream>>>(mixw, MIXH, MIXL, 262144);
  k_transpose_1024<<<dim3(16, 16), 256, 0, stream>>>(projw, PROJH, PROJL);

  // pass 1: Z = (I+K)^-1 in place (f32 — kappa(I+K)~1.6); V = 2Z - I folded downstream
  k_build_aug_f<<<1024, 256, 0, stream>>>(vre, vim, AUGF);
  gj_inv64_p<float2, float><<<9, 1024, 0, stream>>>(AUGF, BINV2F, MCOPY2F);
  for (int s = 0; s < 8; ++s) {
    gj_trans_t<float2><<<7, 256, 0, stream>>>(AUGF, BINV2F + (s & 1)*4096, PIVF, s*64, s);
    gj_upinv<float2, float><<<dim3(8, 8), 1024, 0, stream>>>(AUGF, PIVF, BINV2F, MCOPY2F, s);
  }
  // W built directly into the f64 pass-2 buffer
  k_build_w<<<1024, 256, 0, stream>>>(AUGF, lsig, dw, AUG, WCATH, WCATL);

  // pass 2: W^-1 = in-place GJ on AUG (f64 — kappa(W)~1e4 + no-pivot growth)
  gj_inv64_p<double2, double><<<9, 1024, 0, stream>>>(AUG, BINV2, MCOPY2);
  for (int s = 0; s < 8; ++s) {
    gj_trans_t<double2><<<7, 256, 0, stream>>>(AUG, BINV2 + (s & 1)*4096, PIV, s*64, s);
    gj_upinv<double2, double><<<dim3(8, 8), 1024, 0, stream>>>(AUG, PIV, BINV2, MCOPY2, s);
  }

  // fold matrices (split-f16 GEMMs); AUG now holds W^-1 (512x512 f64)
  k_build_tb<<<1024, 256, 0, stream>>>(AUG, TAB, B1TH, B1TL, B2TH, B2TL);
  k_bias2<<<512, 256, 0, stream>>>(AUG, TAB, projb, BIAS2);
  // BTF[e][k<512] = Re(W diag(t) Winv)[k,e]
  gemm3<1024, 512, 0, 1024, 1536><<<dim3(4, 4), 256, 0, stream>>>(B1TH, B1TL, WCATH, WCATL, BTFH, BTFL, nullptr, nullptr);
  // BTF[e][512+c] = M2[c,e]
  gemm3<1024, 1024, 0, 1024, 1536><<<dim3(8, 4), 256, 0, stream>>>(B2TH, B2TL, PROJH, PROJL, BTFH + 512, BTFL + 512, nullptr, nullptr);
  // BTMIX[n][k] = Mmix[k,n]
  gemm3<1024, 512, 0, 1024, 512><<<dim3(4, 8), 256, 0, stream>>>(MIXH, MIXL, WCATH, WCATL, BTMIXH, BTMIXL, nullptr, nullptr);

  // x_in = x @ Mmix + mix_b  (f32 out)
  gemm3<512, 1024, 3, 1536, 1024><<<dim3(8, 128), 256, 0, stream>>>(ACATH, ACATL, BTMIXH, BTMIXL, nullptr, nullptr, XINF, mixb);

  // scan over T -> states into ACAT hi/lo cols [512,1536)
  k_scan1<<<256, 256, 0, stream>>>(XINF, decre, decim, CARRY);
  k_scan2<<<16, 256, 0, stream>>>(decre, decim, CARRY, PREF);
  k_scan3<<<256, 256, 0, stream>>>(XINF, decre, decim, PREF, ACATH, ACATL);

  // x_out = [x | s_cat] @ BTF^T + bias2   (f32 out)
  gemm3<1536, 512, 2, 1536, 512><<<dim3(4, 128), 256, 0, stream>>>(ACATH, ACATL, BTFH, BTFL, nullptr, nullptr, out, BIAS2);
}

// Round 17
// 2339.542 us; speedup vs baseline: 1.8004x; 1.8004x over previous
//
#include <hip/hip_runtime.h>
#include <hip/hip_bf16.h>

typedef unsigned short u16;
typedef _Float16 f16x8 __attribute__((ext_vector_type(8)));
typedef float f32x4 __attribute__((ext_vector_type(4)));

#define DEV __device__ __forceinline__

DEV u16 f2h(float f) { _Float16 h = (_Float16)f; u16 u; __builtin_memcpy(&u, &h, 2); return u; }
DEV float h2f(u16 u) { _Float16 h; __builtin_memcpy(&h, &u, 2); return (float)h; }
DEV void splitf(float v, u16& hi, u16& lo) { hi = f2h(v); lo = f2h(v - h2f(hi)); }
DEV float sigm(float x) { return 1.f / (1.f + __expf(-x)); }
// direct HBM->LDS 16B DMA: per-lane global src, wave-uniform LDS base + lane*16
DEV void gload16(const u16* g, u16* l) {
  __builtin_amdgcn_global_load_lds((const __attribute__((address_space(1))) void*)g,
                                   (__attribute__((address_space(3))) void*)l, 16, 0, 0);
}

static const int TT = 2048;

// ---------------- workspace layout (bytes) ----------------
static const size_t OFF_AUGF   = 0;                                   // float2 512*512 (2MB) pass-1 in-place
static const size_t OFF_AUG    = OFF_AUGF   + (size_t)512*512*8;      // double2 512*512 (4MB) pass-2 in-place
static const size_t OFF_BINV   = OFF_AUG    + (size_t)512*512*16;     // double2 64*64
static const size_t OFF_PIV    = OFF_BINV   + (size_t)64*64*16;       // double2 64*512
static const size_t OFF_MCOPY  = OFF_PIV    + (size_t)64*512*16;      // double2 512*64
static const size_t OFF_TAB    = OFF_MCOPY  + (size_t)512*64*16;      // double4 512
static const size_t OFF_WCATH  = OFF_TAB    + (size_t)512*32;         // f16 512*1024
static const size_t OFF_WCATL  = OFF_WCATH  + (size_t)512*1024*2;
static const size_t OFF_MIXH   = OFF_WCATL  + (size_t)512*1024*2;     // f16 1024*1024
static const size_t OFF_MIXL   = OFF_MIXH   + (size_t)1024*1024*2;
static const size_t OFF_PROJH  = OFF_MIXL   + (size_t)1024*1024*2;    // f16 1024*1024 (transposed)
static const size_t OFF_PROJL  = OFF_PROJH  + (size_t)1024*1024*2;
static const size_t OFF_B1TH   = OFF_PROJL  + (size_t)1024*1024*2;    // f16 512*1024
static const size_t OFF_B1TL   = OFF_B1TH   + (size_t)512*1024*2;
static const size_t OFF_B2TH   = OFF_B1TL   + (size_t)512*1024*2;
static const size_t OFF_B2TL   = OFF_B2TH   + (size_t)512*1024*2;
static const size_t OFF_BTMIXH = OFF_B2TL   + (size_t)512*1024*2;     // f16 1024*512
static const size_t OFF_BTMIXL = OFF_BTMIXH + (size_t)1024*512*2;
static const size_t OFF_BTFH   = OFF_BTMIXL + (size_t)1024*512*2;     // f16 512*1536
static const size_t OFF_BTFL   = OFF_BTFH   + (size_t)512*1536*2;
static const size_t OFF_BIAS2  = OFF_BTFL   + (size_t)512*1536*2;     // f32 512
static const size_t OFF_CARRY  = OFF_BIAS2  + (size_t)512*4;          // float2 4096*16
static const size_t OFF_PREF   = OFF_CARRY  + (size_t)4096*16*8;      // float2 4096*16
static const size_t OFF_XINF   = OFF_PREF   + (size_t)4096*16*8;      // f32 16384*1024 (64MB)
static const size_t OFF_ACATH  = OFF_XINF   + (size_t)16384*1024*4;   // f16 16384*1536 (48MB)
static const size_t OFF_ACATL  = OFF_ACATH  + (size_t)16384*1536*2;   // f16 16384*1536 (48MB)

// ---------------- converts ----------------
__global__ __launch_bounds__(256) void k_split_f32(const float* __restrict__ s, u16* __restrict__ dh,
                                                   u16* __restrict__ dl, int n4) {
  int g = blockIdx.x * 256 + threadIdx.x;
  if (g >= n4) return;
  float4 v = ((const float4*)s)[g];
  ushort4 h, l;
  splitf(v.x, h.x, l.x); splitf(v.y, h.y, l.y); splitf(v.z, h.z, l.z); splitf(v.w, h.w, l.w);
  ((ushort4*)dh)[g] = h;
  ((ushort4*)dl)[g] = l;
}

// x (16384x512 f32) -> ACAT hi/lo cols [0,512) with row stride 1536
__global__ __launch_bounds__(256) void k_x_to_acat(const float* __restrict__ x, u16* __restrict__ ah,
                                                   u16* __restrict__ al) {
  int g = blockIdx.x * 256 + threadIdx.x;   // 2097152 float4s
  if (g >= 2097152) return;
  float4 v = ((const float4*)x)[g];
  int idx = g * 4;
  int row = idx >> 9, col = idx & 511;
  ushort4 h, l;
  splitf(v.x, h.x, l.x); splitf(v.y, h.y, l.y); splitf(v.z, h.z, l.z); splitf(v.w, h.w, l.w);
  *(ushort4*)(ah + (size_t)row*1536 + col) = h;
  *(ushort4*)(al + (size_t)row*1536 + col) = l;
}

// proj_w (1024x1024 f32) -> hi/lo transposed: out[j][c] = in[c][j]
__global__ __launch_bounds__(256) void k_transpose_1024(const float* __restrict__ in, u16* __restrict__ oh,
                                                        u16* __restrict__ ol) {
  __shared__ float s[64][65];
  int lx = threadIdx.x & 63, ly = threadIdx.x >> 6;
#pragma unroll
  for (int i = 0; i < 16; ++i) {
    int c = blockIdx.y*64 + ly*16 + i;
    s[ly*16 + i][lx] = in[(size_t)c*1024 + blockIdx.x*64 + lx];
  }
  __syncthreads();
#pragma unroll
  for (int i = 0; i < 16; ++i) {
    int j = blockIdx.x*64 + ly*16 + i;
    u16 h, l; splitf(s[lx][ly*16 + i], h, l);
    oh[(size_t)j*1024 + blockIdx.y*64 + lx] = h;
    ol[(size_t)j*1024 + blockIdx.y*64 + lx] = l;
  }
}

// ---------------- build (I+K), K = A - A^H  (f32, 512 cols — pass 1 is a plain inversion) ----------------
__global__ __launch_bounds__(256) void k_build_aug_f(const float* __restrict__ vre, const float* __restrict__ vim,
                                                     float2* __restrict__ aug) {
  int g = blockIdx.x * 256 + threadIdx.x;   // 512*512
  if (g >= 512*512) return;
  int i = g >> 9, j = g & 511;
  float sre = vre[i*512 + j] - vre[j*512 + i];
  float sim = vim[i*512 + j] + vim[j*512 + i];
  float idd = (i == j) ? 1.f : 0.f;
  aug[g] = make_float2(idd + sre, sim);
}

// ---------------- in-place blocked GJ inversion (BS=64, no pivoting), A is 512x512 ----------------
// inv64_p: block 0 inverts the diagonal block in registers (R11-verified v3 math, 1024 thr);
// blocks 1..8 snapshot the pivot COLUMN block M into MCOPY (so update can overwrite it race-free).
template<typename T2, typename TR>
__global__ __launch_bounds__(1024) void gj_inv64_p(const T2* __restrict__ AUG, T2* __restrict__ BINV,
                                                   T2* __restrict__ MCOPY, int k0) {
  if (blockIdx.x > 0) {
    int b = blockIdx.x - 1;
    for (int l = threadIdx.x; l < 4096; l += 1024) {
      int rr = l >> 6, cc = l & 63;
      MCOPY[(size_t)(b*64 + rr)*64 + cc] = AUG[(size_t)(b*64 + rr)*512 + k0 + cc];
    }
    return;
  }
  __shared__ T2 mcol[2][64];
  __shared__ T2 praw[2][68];   // padded: index j + (j>>4)
  const int tid = threadIdx.x;
  const int r = tid >> 4, q = tid & 15;   // row, column-quad (4 cols per thread)
  T2 a[4];
  const T2* src = AUG + (size_t)(k0 + r)*512 + k0 + q*4;
#pragma unroll
  for (int jj = 0; jj < 4; ++jj) a[jj] = src[jj];
  if (q == 0) mcol[0][r] = a[0];
  if (r == 0) {
#pragma unroll
    for (int jj = 0; jj < 4; ++jj) { int j = q*4 + jj; praw[0][j + (j >> 4)] = a[jj]; }
  }
  __syncthreads();
  for (int p = 0; p < 64; ++p) {
    const int bu = p & 1;
    T2 pd = praw[bu][p + (p >> 4)];
    TR inv = TR(1) / (pd.x*pd.x + pd.y*pd.y);
    T2 pinv; pinv.x = pd.x*inv; pinv.y = -pd.y*inv;
    T2 mraw = mcol[bu][r];
    T2 g; g.x = mraw.x*pinv.x - mraw.y*pinv.y; g.y = mraw.x*pinv.y + mraw.y*pinv.x;
    if (r == p) {
#pragma unroll
      for (int jj = 0; jj < 4; ++jj) {
        int j = q*4 + jj;
        T2 v;
        if (j == p) v = pinv;
        else { T2 pr = praw[bu][j + (j >> 4)]; v.x = pr.x*pinv.x - pr.y*pinv.y; v.y = pr.x*pinv.y + pr.y*pinv.x; }
        a[jj] = v;
      }
    } else {
#pragma unroll
      for (int jj = 0; jj < 4; ++jj) {
        int j = q*4 + jj;
        if (j == p) { a[jj].x = -g.x; a[jj].y = -g.y; }
        else {
          T2 pr = praw[bu][j + (j >> 4)];
          a[jj].x -= g.x*pr.x - g.y*pr.y;
          a[jj].y -= g.x*pr.y + g.y*pr.x;
        }
      }
    }
    if (p < 63) {
      const int nbu = bu ^ 1;
      if (q == ((p + 1) >> 2)) {
        const int loc = (p + 1) & 3;
#pragma unroll
        for (int jj = 0; jj < 4; ++jj) if (jj == loc) mcol[nbu][r] = a[jj];   // static index (rule #20)
      }
      if (r == p + 1) {
#pragma unroll
        for (int jj = 0; jj < 4; ++jj) { int j = q*4 + jj; praw[nbu][j + (j >> 4)] = a[jj]; }
      }
    }
    __syncthreads();
  }
  T2* dst = BINV + (size_t)r*64 + q*4;
#pragma unroll
  for (int jj = 0; jj < 4; ++jj) dst[jj] = a[jj];
}

// P[0:64][cols] = Binv @ AUG[k0:k0+64][cols] for the 7 non-pivot 64-col chunks.
template<typename T2>
__global__ __launch_bounds__(256) void gj_trans_t(const T2* __restrict__ AUG, const T2* __restrict__ BINV,
                                                  T2* __restrict__ PIV, int k0, int s) {
  __shared__ T2 binv[64][16];
  int tid = threadIdx.x;
  int cj = blockIdx.x + (blockIdx.x >= s ? 1 : 0);   // skip pivot chunk
  int col = cj*64 + (tid & 63);
  int rsub = tid >> 6;
  T2 acc[16];
#pragma unroll
  for (int i = 0; i < 16; ++i) { acc[i].x = 0; acc[i].y = 0; }
  for (int kc = 0; kc < 4; ++kc) {
    for (int l = tid; l < 1024; l += 256) {
      int rr = l >> 4, cc = l & 15;
      binv[rr][cc] = BINV[(size_t)rr*64 + kc*16 + cc];
    }
    __syncthreads();
#pragma unroll 4
    for (int kk = 0; kk < 16; ++kk) {
      T2 av = AUG[(size_t)(k0 + kc*16 + kk)*512 + col];
#pragma unroll
      for (int i = 0; i < 16; ++i) {
        T2 bv = binv[rsub*16 + i][kk];
        acc[i].x += bv.x*av.x - bv.y*av.y;
        acc[i].y += bv.x*av.y + bv.y*av.x;
      }
    }
    __syncthreads();
  }
#pragma unroll
  for (int i = 0; i < 16; ++i) PIV[(size_t)(rsub*16 + i)*512 + col] = acc[i];
}

// In-place rank-64 update over ALL 8 col chunks. Multipliers come from MCOPY (snapshot),
// so the pivot-column chunk can be overwritten with -M*Binv / Binv race-free.
template<typename T2>
__global__ __launch_bounds__(256) void gj_update_t(T2* __restrict__ AUG, const T2* __restrict__ PIV,
                                                   const T2* __restrict__ BINV, const T2* __restrict__ MCOPY,
                                                   int k0) {
  __shared__ T2 mult[16][64];
  __shared__ T2 pivc[16][64];
  int tid = threadIdx.x;
  int rb = blockIdx.y;
  int cj = blockIdx.x;
  const int s = k0 >> 6;
  const bool ispiv = (cj == s);
  int colBase = cj*64;
  for (int l = tid; l < 1024; l += 256) {
    int rr = l >> 6, kk = l & 63;
    mult[rr][kk] = MCOPY[(size_t)(rb*16 + rr)*64 + kk];
  }
  int ccl = tid & 63, rsub = tid >> 6;
  int col = colBase + ccl;
  T2 acc[4];
  if (ispiv) {
#pragma unroll
    for (int i = 0; i < 4; ++i) { acc[i].x = 0; acc[i].y = 0; }
  } else {
#pragma unroll
    for (int i = 0; i < 4; ++i) acc[i] = AUG[(size_t)(rb*16 + rsub*4 + i)*512 + col];
  }
  for (int kc = 0; kc < 4; ++kc) {
    for (int l = tid; l < 1024; l += 256) {
      int rr = l >> 6, cc = l & 63;
      pivc[rr][cc] = ispiv ? BINV[(size_t)(kc*16 + rr)*64 + cc]
                           : PIV[(size_t)(kc*16 + rr)*512 + colBase + cc];
    }
    __syncthreads();
#pragma unroll 4
    for (int k2 = 0; k2 < 16; ++k2) {
      T2 pv = pivc[k2][ccl];
#pragma unroll
      for (int i = 0; i < 4; ++i) {
        T2 m = mult[rsub*4 + i][kc*16 + k2];
        acc[i].x -= m.x*pv.x - m.y*pv.y;
        acc[i].y -= m.x*pv.y + m.y*pv.x;
      }
    }
    __syncthreads();
  }
#pragma unroll
  for (int i = 0; i < 4; ++i) {
    int gr = rb*16 + rsub*4 + i;
    T2 o = acc[i];
    if (gr >= k0 && gr < k0 + 64) {
      o = ispiv ? BINV[(size_t)(gr - k0)*64 + ccl] : PIV[(size_t)(gr - k0)*512 + col];
    }
    AUG[(size_t)gr*512 + col] = o;
  }
}

// ---------------- W build: V = 2Z - I (Z = (I+K)^-1), + reference f32 DFT phase ----------------
__global__ __launch_bounds__(256) void k_build_w(const float2* __restrict__ augf, const float* __restrict__ lsig,
                                                 const float* __restrict__ dw, double2* __restrict__ w64,
                                                 u16* __restrict__ wch, u16* __restrict__ wcl) {
  int g = blockIdx.x * 256 + threadIdx.x;
  if (g >= 512*512) return;
  int k = g >> 9, j = g & 511;
  float2 Z = augf[(size_t)k*512 + j];
  double Vre = 2.0*(double)Z.x - ((k == j) ? 1.0 : 0.0);
  double Vim = 2.0*(double)Z.y;
  double S = exp((double)lsig[j]);
  double al = 1.0 / (1.0 + exp(-(double)dw[0]));
  double sc = S * (1.0 - al);
  const float n2pi = (float)(-2.0 * 3.14159265358979323846);
  float nk = (float)(k * j);
  float ph32 = (n2pi * nk) / 512.0f;
  double sn, cs; sincos((double)ph32, &sn, &cs);
  float snf = (float)sn, csf = (float)cs;
  float rsq = sqrtf(512.0f);
  float dre = csf / rsq;
  float dimv = snf / rsq;
  double2 w = make_double2(Vre*sc + (double)dre*al, Vim*sc + (double)dimv*al);
  w64[(size_t)k*512 + j] = w;
  u16 h, l;
  splitf((float)w.x, h, l);
  wch[(size_t)k*1024 + j] = h;  wcl[(size_t)k*1024 + j] = l;
  splitf((float)w.y, h, l);
  wch[(size_t)k*1024 + 512 + j] = h;  wcl[(size_t)k*1024 + 512 + j] = l;
}

// ---------------- per-d constants (t_decay, forcing) in f64 ----------------
__global__ __launch_bounds__(256) void k_const512(const float* __restrict__ lamre, const float* __restrict__ lamim,
                                                  double4* __restrict__ tab) {
  int g = blockIdx.x * 256 + threadIdx.x;
  if (g >= 512) return;
  double lr = fmin(fmax((double)lamre[g], -0.3), 0.3);
  double li = (double)lamim[g];
  double e = exp(lr);
  double sn, cs; sincos(li, &sn, &cs);
  double tdre = e*cs, tdim = e*sn;
  double sgn = (lr + 1e-12) >= 0.0 ? 1.0 : -1.0;
  double lsr = lr + 1e-8*sgn, lsi = li;
  double numr = tdre - 1.0, numi = tdim;
  double idn = 1.0 / (lsr*lsr + lsi*lsi);
  double fr = (numr*lsr + numi*lsi)*idn;
  double fi = (numi*lsr - numr*lsi)*idn;
  tab[g] = make_double4(tdre, tdim, fr, fi);
}

// B1T[e][m]=Re(t_m Winv[m,e]), B1T[e][512+m]=-Im(...); B2T same with f_m  (hi/lo)
__global__ __launch_bounds__(256) void k_build_tb(const double2* __restrict__ winv, const double4* __restrict__ tab,
                                                  u16* __restrict__ b1h, u16* __restrict__ b1l,
                                                  u16* __restrict__ b2h, u16* __restrict__ b2l) {
  int g = blockIdx.x * 256 + threadIdx.x;   // 512*512, e fast
  if (g >= 512*512) return;
  int e = g & 511, m = g >> 9;
  double2 wv = winv[(size_t)m*512 + e];
  double4 tb = tab[m];
  double twre = tb.x*wv.x - tb.y*wv.y, twim = tb.x*wv.y + tb.y*wv.x;
  double fwre = tb.z*wv.x - tb.w*wv.y, fwim = tb.z*wv.y + tb.w*wv.x;
  u16 h, l;
  splitf((float)twre, h, l);  b1h[(size_t)e*1024 + m] = h;        b1l[(size_t)e*1024 + m] = l;
  splitf((float)-twim, h, l); b1h[(size_t)e*1024 + 512 + m] = h;  b1l[(size_t)e*1024 + 512 + m] = l;
  splitf((float)fwre, h, l);  b2h[(size_t)e*1024 + m] = h;        b2l[(size_t)e*1024 + m] = l;
  splitf((float)-fwim, h, l); b2h[(size_t)e*1024 + 512 + m] = h;  b2l[(size_t)e*1024 + 512 + m] = l;
}

// bias2[e] = Re( sum_d (projb[d]+i projb[512+d]) * f_d * Winv[d,e] )  — one block per e
__global__ __launch_bounds__(256) void k_bias2(const double2* __restrict__ winv, const double4* __restrict__ tab,
                                               const float* __restrict__ projb, float* __restrict__ bias2) {
  int e = blockIdx.x;
  int t = threadIdx.x;
  double acc = 0.0;
  for (int d = t; d < 512; d += 256) {
    double2 wv = winv[(size_t)d*512 + e];
    double4 tb = tab[d];
    double fwre = tb.z*wv.x - tb.w*wv.y;
    double fwim = tb.z*wv.y + tb.w*wv.x;
    acc += (double)projb[d]*fwre - (double)projb[512 + d]*fwim;
  }
#pragma unroll
  for (int off = 32; off; off >>= 1) acc += __shfl_down(acc, off, 64);
  __shared__ double red[4];
  if ((t & 63) == 0) red[t >> 6] = acc;
  __syncthreads();
  if (t == 0) bias2[e] = (float)(red[0] + red[1] + red[2] + red[3]);
}

// ---------------- split-f16 MFMA GEMM: C = (Ah+Al)(Bh+Bl)^T, drop Al*Bl ----------------
// Staging via global_load_lds (no VGPR staging, no spill); XCD-chunk block swizzle.
// EPI: 0 = hi/lo f16 store; 2/3 = f32 store + bias
template<int K, int NOUT, int EPI, int LDA, int LDO>
__global__ __launch_bounds__(256) void gemm3(const u16* __restrict__ Ah, const u16* __restrict__ Al,
                                             const u16* __restrict__ Bh, const u16* __restrict__ Bl,
                                             u16* __restrict__ outH, u16* __restrict__ outL,
                                             float* __restrict__ outF, const float* __restrict__ bias) {
  __shared__ alignas(16) u16 Ash[128*64];
  __shared__ alignas(16) u16 Asl[128*64];
  __shared__ alignas(16) u16 Bsh[128*64];
  __shared__ alignas(16) u16 Bsl[128*64];
  const int tid = threadIdx.x;
  const int lane = tid & 63, wid = tid >> 6;
  const int wr = wid >> 1, wc = wid & 1;
  const int nwg = gridDim.x * gridDim.y;
  const int flatb = blockIdx.y * gridDim.x + blockIdx.x;
  const int chunk = nwg >> 3;
  const int swz = (flatb & 7) * chunk + (flatb >> 3);
  const int rowTile = (swz / gridDim.x) * 128;
  const int colTile = (swz % gridDim.x) * 128;
  f32x4 zz = {0.f, 0.f, 0.f, 0.f};
  f32x4 acc[4][4];
#pragma unroll
  for (int m = 0; m < 4; ++m)
#pragma unroll
    for (int n = 0; n < 4; ++n) acc[m][n] = zz;

  const int KT = K / 64;
  for (int kt = 0; kt < KT; ++kt) {
    const int k0 = kt * 64;
    __syncthreads();   // previous tile fully consumed
#pragma unroll
    for (int i = 0; i < 4; ++i) {
      int flat = i*256 + tid;
      int ar = flat >> 3;
      int as = (flat & 7) ^ (ar & 7);       // pre-swizzled global slot
      size_t aoff = (size_t)(rowTile + ar)*LDA + (k0 + as*8);
      size_t boff = (size_t)(colTile + ar)*K   + (k0 + as*8);
      int lb = (i*256 + (tid & ~63)) * 8;   // wave-uniform LDS base (u16 units)
      gload16(Ah + aoff, Ash + lb);
      gload16(Al + aoff, Asl + lb);
      gload16(Bh + boff, Bsh + lb);
      gload16(Bl + boff, Bsl + lb);
    }
    __syncthreads();   // drains vmcnt before LDS reads
#pragma unroll
    for (int ks = 0; ks < 2; ++ks) {
      f16x8 afh[4], afl[4], bfh[4], bfl[4];
#pragma unroll
      for (int m = 0; m < 4; ++m) {
        int row = wr*64 + m*16 + (lane & 15);
        int off = row*128 + (((ks*4 + (lane >> 4)) ^ (row & 7)) << 4);
        afh[m] = *(const f16x8*)((const char*)Ash + off);
        afl[m] = *(const f16x8*)((const char*)Asl + off);
      }
#pragma unroll
      for (int n = 0; n < 4; ++n) {
        int row = wc*64 + n*16 + (lane & 15);
        int off = row*128 + (((ks*4 + (lane >> 4)) ^ (row & 7)) << 4);
        bfh[n] = *(const f16x8*)((const char*)Bsh + off);
        bfl[n] = *(const f16x8*)((const char*)Bsl + off);
      }
#pragma unroll
      for (int m = 0; m < 4; ++m)
#pragma unroll
        for (int n = 0; n < 4; ++n) {
          acc[m][n] = __builtin_amdgcn_mfma_f32_16x16x32_f16(afl[m], bfh[n], acc[m][n], 0, 0, 0);
          acc[m][n] = __builtin_amdgcn_mfma_f32_16x16x32_f16(afh[m], bfl[n], acc[m][n], 0, 0, 0);
          acc[m][n] = __builtin_amdgcn_mfma_f32_16x16x32_f16(afh[m], bfh[n], acc[m][n], 0, 0, 0);
        }
    }
  }
  const int colBase = colTile + wc*64;
  const int rowBase = rowTile + wr*64 + (lane >> 4)*4;
#pragma unroll
  for (int n = 0; n < 4; ++n) {
    int col = colBase + n*16 + (lane & 15);
    float bv = (EPI >= 2) ? bias[col] : 0.f;
#pragma unroll
    for (int m = 0; m < 4; ++m) {
#pragma unroll
      for (int j = 0; j < 4; ++j) {
        int row = rowBase + m*16 + j;
        float v = acc[m][n][j] + bv;
        if (EPI >= 2) {
          outF[(size_t)row*LDO + col] = v;
        } else {
          u16 h, l; splitf(v, h, l);
          outH[(size_t)row*LDO + col] = h;
          outL[(size_t)row*LDO + col] = l;
        }
      }
    }
  }
}

// ---------------- chunked linear scan along T (XIN is f32) ----------------
__global__ __launch_bounds__(256) void k_scan1(const float* __restrict__ xin, const float* __restrict__ dre_,
                                               const float* __restrict__ dim_, float2* __restrict__ carry) {
  int g = blockIdx.x * 256 + threadIdx.x;   // 65536
  int d = g & 511; int rr = g >> 9; int b = rr & 7; int c = rr >> 3;
  float dre = sigm(dre_[d]);
  float dim = dim_[d];
  size_t base = ((size_t)(b*TT + c*128))*1024 + d;
  float sre = 0.f, sim = 0.f;
  for (int t = 0; t < 128; ++t) {
    float xre = xin[base];
    float xim = xin[base + 512];
    float nre = dre*sre - dim*sim + xre;
    float nim = dre*sim + dim*sre + xim;
    sre = nre; sim = nim;
    base += 1024;
  }
  carry[((size_t)(b*512 + d))*16 + c] = make_float2(sre, sim);
}

__global__ __launch_bounds__(256) void k_scan2(const float* __restrict__ dre_, const float* __restrict__ dim_,
                                               const float2* __restrict__ carry, float2* __restrict__ pref) {
  int g = blockIdx.x * 256 + threadIdx.x;   // 4096
  int d = g & 511; int b = g >> 9;
  float dre = sigm(dre_[d]);
  float dim = dim_[d];
  float are = dre, aim = dim;
#pragma unroll
  for (int i = 0; i < 7; ++i) { float nr = are*are - aim*aim; float ni = 2.f*are*aim; are = nr; aim = ni; }
  float sre = 0.f, sim = 0.f;
  size_t base = ((size_t)(b*512 + d))*16;
  for (int c = 0; c < 16; ++c) {
    pref[base + c] = make_float2(sre, sim);
    float2 cr = carry[base + c];
    float nr = are*sre - aim*sim + cr.x;
    float ni = are*sim + aim*sre + cr.y;
    sre = nr; sim = ni;
  }
}

// writes states into ACAT hi/lo cols [512,1536)
__global__ __launch_bounds__(256) void k_scan3(const float* __restrict__ xin, const float* __restrict__ dre_,
                                               const float* __restrict__ dim_, const float2* __restrict__ pref,
                                               u16* __restrict__ ah, u16* __restrict__ al) {
  int g = blockIdx.x * 256 + threadIdx.x;   // 65536
  int d = g & 511; int rr = g >> 9; int b = rr & 7; int c = rr >> 3;
  float dre = sigm(dre_[d]);
  float dim = dim_[d];
  float2 p0 = pref[((size_t)(b*512 + d))*16 + c];
  float sre = p0.x, sim = p0.y;
  size_t base  = ((size_t)(b*TT + c*128))*1024 + d;
  size_t base2 = ((size_t)(b*TT + c*128))*1536 + d;
  for (int t = 0; t < 128; ++t) {
    float xre = xin[base];
    float xim = xin[base + 512];
    float nre = dre*sre - dim*sim + xre;
    float nim = dre*sim + dim*sre + xim;
    sre = nre; sim = nim;
    u16 h, l;
    splitf(sre, h, l); ah[base2 + 512]  = h; al[base2 + 512]  = l;
    splitf(sim, h, l); ah[base2 + 1024] = h; al[base2 + 1024] = l;
    base += 1024; base2 += 1536;
  }
}

// ---------------- launch ----------------
extern "C" void kernel_launch(void* const* d_in, const int* in_sizes, int n_in,
                              void* d_out, int out_size, void* d_ws, size_t ws_size,
                              hipStream_t stream) {
  (void)in_sizes; (void)n_in; (void)out_size; (void)ws_size;
  const float* x     = (const float*)d_in[0];
  const float* vre   = (const float*)d_in[1];
  const float* vim   = (const float*)d_in[2];
  const float* lsig  = (const float*)d_in[3];
  const float* dw    = (const float*)d_in[4];
  const float* decre = (const float*)d_in[5];
  const float* decim = (const float*)d_in[6];
  const float* mixw  = (const float*)d_in[7];
  const float* mixb  = (const float*)d_in[8];
  const float* projw = (const float*)d_in[9];
  const float* projb = (const float*)d_in[10];
  const float* lamre = (const float*)d_in[11];
  const float* lamim = (const float*)d_in[12];
  float* out = (float*)d_out;
  char* ws = (char*)d_ws;

  float2*  AUGF   = (float2*)(ws + OFF_AUGF);
  double2* AUG    = (double2*)(ws + OFF_AUG);
  double2* BINV   = (double2*)(ws + OFF_BINV);
  float2*  BINVF  = (float2*)(ws + OFF_BINV);
  double2* PIV    = (double2*)(ws + OFF_PIV);
  float2*  PIVF   = (float2*)(ws + OFF_PIV);
  double2* MCOPY  = (double2*)(ws + OFF_MCOPY);
  float2*  MCOPYF = (float2*)(ws + OFF_MCOPY);
  double4* TAB    = (double4*)(ws + OFF_TAB);
  u16*    WCATH  = (u16*)(ws + OFF_WCATH);
  u16*    WCATL  = (u16*)(ws + OFF_WCATL);
  u16*    MIXH   = (u16*)(ws + OFF_MIXH);
  u16*    MIXL   = (u16*)(ws + OFF_MIXL);
  u16*    PROJH  = (u16*)(ws + OFF_PROJH);
  u16*    PROJL  = (u16*)(ws + OFF_PROJL);
  u16*    B1TH   = (u16*)(ws + OFF_B1TH);
  u16*    B1TL   = (u16*)(ws + OFF_B1TL);
  u16*    B2TH   = (u16*)(ws + OFF_B2TH);
  u16*    B2TL   = (u16*)(ws + OFF_B2TL);
  u16*    BTMIXH = (u16*)(ws + OFF_BTMIXH);
  u16*    BTMIXL = (u16*)(ws + OFF_BTMIXL);
  u16*    BTFH   = (u16*)(ws + OFF_BTFH);
  u16*    BTFL   = (u16*)(ws + OFF_BTFL);
  float*  BIAS2  = (float*)(ws + OFF_BIAS2);
  float2* CARRY  = (float2*)(ws + OFF_CARRY);
  float2* PREF   = (float2*)(ws + OFF_PREF);
  float*  XINF   = (float*)(ws + OFF_XINF);
  u16*    ACATH  = (u16*)(ws + OFF_ACATH);
  u16*    ACATL  = (u16*)(ws + OFF_ACATL);

  // independent converts / tables
  k_const512<<<2, 256, 0, stream>>>(lamre, lamim, TAB);
  k_x_to_acat<<<8192, 256, 0, stream>>>(x, ACATH, ACATL);
  k_split_f32<<<1024, 256, 0, stream>>>(mixw, MIXH, MIXL, 262144);
  k_transpose_1024<<<dim3(16, 16), 256, 0, stream>>>(projw, PROJH, PROJL);

  // pass 1: Z = (I+K)^-1 in place (f32 — kappa(I+K)~1.6); V = 2Z - I folded downstream
  k_build_aug_f<<<1024, 256, 0, stream>>>(vre, vim, AUGF);
  for (int s = 0; s < 8; ++s) {
    int k0 = s * 64;
    gj_inv64_p<float2, float><<<9, 1024, 0, stream>>>(AUGF, BINVF, MCOPYF, k0);
    gj_trans_t<float2><<<7, 256, 0, stream>>>(AUGF, BINVF, PIVF, k0, s);
    gj_update_t<float2><<<dim3(8, 32), 256, 0, stream>>>(AUGF, PIVF, BINVF, MCOPYF, k0);
  }
  // W built directly into the f64 pass-2 buffer (no WMAT, no aug2 copy)
  k_build_w<<<1024, 256, 0, stream>>>(AUGF, lsig, dw, AUG, WCATH, WCATL);

  // pass 2: W^-1 = in-place GJ on AUG (f64 — kappa(W)~1e4 + no-pivot growth)
  for (int s = 0; s < 8; ++s) {
    int k0 = s * 64;
    gj_inv64_p<double2, double><<<9, 1024, 0, stream>>>(AUG, BINV, MCOPY, k0);
    gj_trans_t<double2><<<7, 256, 0, stream>>>(AUG, BINV, PIV, k0, s);
    gj_update_t<double2><<<dim3(8, 32), 256, 0, stream>>>(AUG, PIV, BINV, MCOPY, k0);
  }

  // fold matrices (split-f16 GEMMs); AUG now holds W^-1 (512x512 f64)
  k_build_tb<<<1024, 256, 0, stream>>>(AUG, TAB, B1TH, B1TL, B2TH, B2TL);
  k_bias2<<<512, 256, 0, stream>>>(AUG, TAB, projb, BIAS2);
  // BTF[e][k<512] = Re(W diag(t) Winv)[k,e]
  gemm3<1024, 512, 0, 1024, 1536><<<dim3(4, 4), 256, 0, stream>>>(B1TH, B1TL, WCATH, WCATL, BTFH, BTFL, nullptr, nullptr);
  // BTF[e][512+c] = M2[c,e]
  gemm3<1024, 1024, 0, 1024, 1536><<<dim3(8, 4), 256, 0, stream>>>(B2TH, B2TL, PROJH, PROJL, BTFH + 512, BTFL + 512, nullptr, nullptr);
  // BTMIX[n][k] = Mmix[k,n]
  gemm3<1024, 512, 0, 1024, 512><<<dim3(4, 8), 256, 0, stream>>>(MIXH, MIXL, WCATH, WCATL, BTMIXH, BTMIXL, nullptr, nullptr);

  // x_in = x @ Mmix + mix_b  (f32 out)
  gemm3<512, 1024, 3, 1536, 1024><<<dim3(8, 128), 256, 0, stream>>>(ACATH, ACATL, BTMIXH, BTMIXL, nullptr, nullptr, XINF, mixb);

  // scan over T -> states into ACAT hi/lo cols [512,1536)
  k_scan1<<<256, 256, 0, stream>>>(XINF, decre, decim, CARRY);
  k_scan2<<<16, 256, 0, stream>>>(decre, decim, CARRY, PREF);
  k_scan3<<<256, 256, 0, stream>>>(XINF, decre, decim, PREF, ACATH, ACATL);

  // x_out = [x | s_cat] @ BTF^T + bias2   (f32 out)
  gemm3<1536, 512, 2, 1536, 512><<<dim3(4, 128), 256, 0, stream>>>(ACATH, ACATL, BTFH, BTFL, nullptr, nullptr, out, BIAS2);
}